// Round 2
// baseline (675.385 us; speedup 1.0000x reference)
//
#include <hip/hip_runtime.h>

typedef __bf16 bf16_t;
typedef __bf16 bf16x8 __attribute__((ext_vector_type(8)));
typedef float  f32x4  __attribute__((ext_vector_type(4)));

#define NB    64
#define EB    4032            // NB*(NB-1)
#define BATCH 32
#define H     256
#define M_EDGE (BATCH*EB)     // 129024
#define M_NODE (BATCH*NB)     // 2048

// ---------------------------------------------------------------------------
// C[M,256] = ELU(A[M,K] @ W[K,256] + b). Wt is W transposed+bf16: [256,K].
// AMODE 0: direct A0 (lda=K)       (AF32: A0 is fp32, else bf16)
// AMODE 1: concat2  -> k<256: x1[sender], else x1[receiver]     (K=512, bf16)
// AMODE 2: concat3  -> x3[sender] | x3[receiver] | skip[m]      (K=768, bf16)
// STATS: accumulate per-column sum/sumsq of post-ELU output into stats[0..511]
// Output is bf16 (intermediate activations live in bf16).
// ---------------------------------------------------------------------------
template<int AMODE, bool STATS, bool AF32>
__global__ __launch_bounds__(256)
void gemm_elu(const void* __restrict__ A0v, const bf16_t* __restrict__ A1,
              const bf16_t* __restrict__ Wt, const float* __restrict__ bias,
              bf16_t* __restrict__ out, float* __restrict__ stats, int K)
{
    const int m0   = blockIdx.x * 128;
    const int n0   = blockIdx.y * 128;
    const int tid  = threadIdx.x;
    const int wave = tid >> 6, lane = tid & 63;
    const int wr   = wave >> 1, wc = wave & 1;
    const int l15  = lane & 15, quad = lane >> 4;

    __shared__ bf16_t As[128 * 40];   // +8 bf16 pad: 16B-aligned rows, breaks bank stride
    __shared__ bf16_t Bs[128 * 40];

    // per-pass staging geometry (id -> row r, chunk c8); hoist edge-index divides
    int rowv[2], c8v[2], sndOff[2], rcvOff[2];
#pragma unroll
    for (int p = 0; p < 2; ++p) {
        int id = p * 256 + tid;
        rowv[p] = id >> 2;
        c8v[p]  = id & 3;
        if (AMODE != 0) {
            int m  = m0 + rowv[p];
            int bb = m / EB;  int e  = m - bb * EB;
            int sn = e / (NB - 1); int rr = e - sn * (NB - 1);
            int rc = rr + (rr >= sn ? 1 : 0);
            sndOff[p] = (bb * NB + sn) * H;
            rcvOff[p] = (bb * NB + rc) * H;
        }
    }

    f32x4 acc[4][4] = {};

    for (int k0 = 0; k0 < K; k0 += 32) {
#pragma unroll
        for (int p = 0; p < 2; ++p) {
            int r  = rowv[p];
            int kk = k0 + c8v[p] * 8;
            if (AF32) {
                const float* af = (const float*)A0v + (size_t)(m0 + r) * K + kk;
                float4 lo = *(const float4*)af;
                float4 hi = *(const float4*)(af + 4);
                bf16x8 v;
                v[0] = (bf16_t)lo.x; v[1] = (bf16_t)lo.y; v[2] = (bf16_t)lo.z; v[3] = (bf16_t)lo.w;
                v[4] = (bf16_t)hi.x; v[5] = (bf16_t)hi.y; v[6] = (bf16_t)hi.z; v[7] = (bf16_t)hi.w;
                *(bf16x8*)&As[r * 40 + c8v[p] * 8] = v;
            } else {
                const bf16_t* A0 = (const bf16_t*)A0v;
                const bf16_t* asrc;
                if (AMODE == 0) {
                    asrc = A0 + (size_t)(m0 + r) * K + kk;
                } else if (AMODE == 1) {
                    asrc = (kk < H) ? (A0 + sndOff[p] + kk)
                                    : (A0 + rcvOff[p] + (kk - H));
                } else {
                    if (kk < H)          asrc = A0 + sndOff[p] + kk;
                    else if (kk < 2 * H) asrc = A0 + rcvOff[p] + (kk - H);
                    else                 asrc = A1 + (size_t)(m0 + r) * H + (kk - 2 * H);
                }
                *(uint4*)&As[r * 40 + c8v[p] * 8] = *(const uint4*)asrc;
            }
            *(uint4*)&Bs[r * 40 + c8v[p] * 8] = *(const uint4*)(Wt + (size_t)(n0 + r) * K + kk);
        }
        __syncthreads();

        bf16x8 af[4], bfr[4];
#pragma unroll
        for (int t = 0; t < 4; ++t)
            af[t] = *(const bf16x8*)&As[(wr * 64 + t * 16 + l15) * 40 + quad * 8];
#pragma unroll
        for (int u = 0; u < 4; ++u)
            bfr[u] = *(const bf16x8*)&Bs[(wc * 64 + u * 16 + l15) * 40 + quad * 8];
#pragma unroll
        for (int t = 0; t < 4; ++t)
#pragma unroll
            for (int u = 0; u < 4; ++u)
                acc[t][u] = __builtin_amdgcn_mfma_f32_16x16x32_bf16(af[t], bfr[u], acc[t][u], 0, 0, 0);
        __syncthreads();
    }

    // epilogue: bias + ELU + store + (optional) BN stats
#pragma unroll
    for (int u = 0; u < 4; ++u) {
        int   col = n0 + wc * 64 + u * 16 + l15;
        float bv  = bias[col];
        float s = 0.f, q = 0.f;
#pragma unroll
        for (int t = 0; t < 4; ++t) {
            int rowb = m0 + wr * 64 + t * 16 + quad * 4;
#pragma unroll
            for (int r = 0; r < 4; ++r) {
                float v = acc[t][u][r] + bv;
                v = v > 0.f ? v : expm1f(v);
                out[(size_t)(rowb + r) * H + col] = (bf16_t)v;
                if (STATS) { s += v; q += v * v; }
            }
        }
        if (STATS) {
            s += __shfl_xor(s, 16); s += __shfl_xor(s, 32);
            q += __shfl_xor(q, 16); q += __shfl_xor(q, 32);
            if (quad == 0) {
                atomicAdd(&stats[col], s);
                atomicAdd(&stats[H + col], q);
            }
        }
    }
}

// ---------------------------------------------------------------------------
__global__ void zero_stats(float* s) { s[blockIdx.x * 256 + threadIdx.x] = 0.f; }

// w[K,256] fp32 -> wt[256,K] bf16
__global__ void transpose_w(const float* __restrict__ w, bf16_t* __restrict__ wt, int K)
{
    int idx = blockIdx.x * 256 + threadIdx.x;   // grid = K blocks, exact
    int k = idx >> 8, n = idx & 255;
    wt[n * K + k] = (bf16_t)w[idx];
}

// scale = g*rsqrt(var+eps); shift = beta - mean*scale
__global__ void bn_finalize(const float* __restrict__ stats,
                            const float* __restrict__ g, const float* __restrict__ beta,
                            float M, float* __restrict__ sc)
{
    int c = threadIdx.x;
    float mean = stats[c] / M;
    float var  = stats[H + c] / M - mean * mean;
    float scale = g[c] * rsqrtf(var + 1e-5f);
    sc[c]     = scale;
    sc[H + c] = beta[c] - mean * scale;
}

// in-place x = x*scale[c] + shift[c], 8 bf16 elems/thread
__global__ void bn_apply(bf16_t* __restrict__ x, const float* __restrict__ sc, int nvec)
{
    int i = blockIdx.x * 256 + threadIdx.x;
    if (i >= nvec) return;
    uint4 v = ((uint4*)x)[i];
    bf16_t* e = (bf16_t*)&v;
    int cb = (i * 8) & 255;
#pragma unroll
    for (int j = 0; j < 8; ++j)
        e[j] = (bf16_t)((float)e[j] * sc[cb + j] + sc[H + cb + j]);
    ((uint4*)x)[i] = v;
}

// inc[b,n,c] = (1/64) * sum over edges with receiver n of x2[b,e,c]
__global__ void edge2node(const bf16_t* __restrict__ x2, bf16_t* __restrict__ inc)
{
    int bn = blockIdx.x;             // b*64+n
    int bb = bn >> 6, n = bn & 63;
    int c  = threadIdx.x;
    const bf16_t* base = x2 + (size_t)bb * EB * H;
    float acc = 0.f;
    for (int i = 0; i < NB; ++i) {
        if (i == n) continue;
        int e = i * (NB - 1) + n - (n > i ? 1 : 0);
        acc += (float)base[(size_t)e * H + c];
    }
    inc[(size_t)bn * H + c] = (bf16_t)(acc * (1.f / 64.f));
}

// out[m,0:2] = (x4[m,:]*scale+shift) @ fc_w + fc_b   (BN4 folded in), fp32 out
__global__ void fc_kernel(const bf16_t* __restrict__ x4, const float* __restrict__ sc,
                          const float* __restrict__ fcw, const float* __restrict__ fcb,
                          float* __restrict__ out)
{
    int row  = blockIdx.x * 4 + (threadIdx.x >> 6);
    int lane = threadIdx.x & 63;
    const bf16_t* xr = x4 + (size_t)row * H;
    float s0 = 0.f, s1 = 0.f;
#pragma unroll
    for (int j = 0; j < 4; ++j) {
        int c = j * 64 + lane;
        float v = (float)xr[c] * sc[c] + sc[H + c];
        s0 += v * fcw[c * 2];
        s1 += v * fcw[c * 2 + 1];
    }
#pragma unroll
    for (int off = 32; off; off >>= 1) {
        s0 += __shfl_down(s0, off);
        s1 += __shfl_down(s1, off);
    }
    if (lane == 0) {
        out[(size_t)row * 2]     = s0 + fcb[0];
        out[(size_t)row * 2 + 1] = s1 + fcb[1];
    }
}

// ---------------------------------------------------------------------------
extern "C" void kernel_launch(void* const* d_in, const int* in_sizes, int n_in,
                              void* d_out, int out_size, void* d_ws, size_t ws_size,
                              hipStream_t stream)
{
    (void)in_sizes; (void)n_in; (void)out_size; (void)ws_size;
    const float* inp = (const float*)d_in[0];
    // d_in[1]=rel_rec, d_in[2]=rel_send: deterministic one-hots, indices computed analytically
    const float* w1a = (const float*)d_in[3];  const float* b1a = (const float*)d_in[4];
    const float* w1b = (const float*)d_in[5];  const float* b1b = (const float*)d_in[6];
    const float* g1  = (const float*)d_in[7];  const float* be1 = (const float*)d_in[8];
    const float* w2a = (const float*)d_in[9];  const float* b2a = (const float*)d_in[10];
    const float* w2b = (const float*)d_in[11]; const float* b2b = (const float*)d_in[12];
    const float* g2  = (const float*)d_in[13]; const float* be2 = (const float*)d_in[14];
    const float* w3a = (const float*)d_in[15]; const float* b3a = (const float*)d_in[16];
    const float* w3b = (const float*)d_in[17]; const float* b3b = (const float*)d_in[18];
    const float* g3  = (const float*)d_in[19]; const float* be3 = (const float*)d_in[20];
    const float* w4a = (const float*)d_in[21]; const float* b4a = (const float*)d_in[22];
    const float* w4b = (const float*)d_in[23]; const float* b4b = (const float*)d_in[24];
    const float* g4  = (const float*)d_in[25]; const float* be4 = (const float*)d_in[26];
    const float* fcw = (const float*)d_in[27]; const float* fcb = (const float*)d_in[28];

    char* p = (char*)d_ws;
    auto alloc = [&](size_t nbytes) { char* r = p; p += (nbytes + 255) & ~(size_t)255; return r; };

    bf16_t* wt1a = (bf16_t*)alloc(256 * 256 * 2);
    bf16_t* wt1b = (bf16_t*)alloc(256 * 256 * 2);
    bf16_t* wt2a = (bf16_t*)alloc(512 * 256 * 2);
    bf16_t* wt2b = (bf16_t*)alloc(256 * 256 * 2);
    bf16_t* wt3a = (bf16_t*)alloc(256 * 256 * 2);
    bf16_t* wt3b = (bf16_t*)alloc(256 * 256 * 2);
    bf16_t* wt4a = (bf16_t*)alloc(768 * 256 * 2);
    bf16_t* wt4b = (bf16_t*)alloc(256 * 256 * 2);
    float*  stats = (float*)alloc(4 * 512 * sizeof(float));
    float*  sc    = (float*)alloc(4 * 512 * sizeof(float));
    bf16_t* hn   = (bf16_t*)alloc((size_t)M_NODE * H * 2);
    bf16_t* x1   = (bf16_t*)alloc((size_t)M_NODE * H * 2);
    bf16_t* incb = (bf16_t*)alloc((size_t)M_NODE * H * 2);
    bf16_t* x3   = (bf16_t*)alloc((size_t)M_NODE * H * 2);
    bf16_t* bufA = (bf16_t*)alloc((size_t)M_EDGE * H * 2);
    bf16_t* bufB = (bf16_t*)alloc((size_t)M_EDGE * H * 2);

    zero_stats<<<8, 256, 0, stream>>>(stats);
    transpose_w<<<256, 256, 0, stream>>>(w1a, wt1a, 256);
    transpose_w<<<256, 256, 0, stream>>>(w1b, wt1b, 256);
    transpose_w<<<512, 256, 0, stream>>>(w2a, wt2a, 512);
    transpose_w<<<256, 256, 0, stream>>>(w2b, wt2b, 256);
    transpose_w<<<256, 256, 0, stream>>>(w3a, wt3a, 256);
    transpose_w<<<256, 256, 0, stream>>>(w3b, wt3b, 256);
    transpose_w<<<768, 256, 0, stream>>>(w4a, wt4a, 768);
    transpose_w<<<256, 256, 0, stream>>>(w4b, wt4b, 256);

    dim3 gN(M_NODE / 128, 2), gE(M_EDGE / 128, 2);

    // MLP1 (nodes)
    gemm_elu<0, false, true ><<<gN, 256, 0, stream>>>(inp, nullptr, wt1a, b1a, hn, nullptr, 256);
    gemm_elu<0, true,  false><<<gN, 256, 0, stream>>>(hn,  nullptr, wt1b, b1b, x1, stats + 0, 256);
    bn_finalize<<<1, 256, 0, stream>>>(stats + 0, g1, be1, (float)M_NODE, sc + 0);
    bn_apply<<<M_NODE * H / 8 / 256, 256, 0, stream>>>(x1, sc + 0, M_NODE * H / 8);

    // MLP2 (edges, concat[send,recv])
    gemm_elu<1, false, false><<<gE, 256, 0, stream>>>(x1, nullptr, wt2a, b2a, bufA, nullptr, 512);
    gemm_elu<0, true,  false><<<gE, 256, 0, stream>>>(bufA, nullptr, wt2b, b2b, bufB, stats + 512, 256);
    bn_finalize<<<1, 256, 0, stream>>>(stats + 512, g2, be2, (float)M_EDGE, sc + 512);
    bn_apply<<<M_EDGE * H / 8 / 256, 256, 0, stream>>>(bufB, sc + 512, M_EDGE * H / 8);
    // bufB = x_skip (post-BN)

    // edge2node + MLP3 (nodes)
    edge2node<<<M_NODE, 256, 0, stream>>>(bufB, incb);
    gemm_elu<0, false, false><<<gN, 256, 0, stream>>>(incb, nullptr, wt3a, b3a, hn, nullptr, 256);
    gemm_elu<0, true,  false><<<gN, 256, 0, stream>>>(hn,   nullptr, wt3b, b3b, x3, stats + 1024, 256);
    bn_finalize<<<1, 256, 0, stream>>>(stats + 1024, g3, be3, (float)M_NODE, sc + 1024);
    bn_apply<<<M_NODE * H / 8 / 256, 256, 0, stream>>>(x3, sc + 1024, M_NODE * H / 8);

    // MLP4 (edges, concat[send,recv,skip])
    gemm_elu<2, false, false><<<gE, 256, 0, stream>>>(x3, bufB, wt4a, b4a, bufA, nullptr, 768);
    gemm_elu<0, true,  false><<<gE, 256, 0, stream>>>(bufA, nullptr, wt4b, b4b, bufB, stats + 1536, 256);
    bn_finalize<<<1, 256, 0, stream>>>(stats + 1536, g4, be4, (float)M_EDGE, sc + 1536);

    // final fc with BN4 folded into the load, fp32 output
    fc_kernel<<<M_EDGE / 4, 256, 0, stream>>>(bufB, sc + 1536, fcw, fcb, (float*)d_out);
}

// Round 3
// 511.950 us; speedup vs baseline: 1.3192x; 1.3192x over previous
//
#include <hip/hip_runtime.h>

typedef __bf16 bf16_t;
typedef __bf16 bf16x8 __attribute__((ext_vector_type(8)));
typedef float  f32x4  __attribute__((ext_vector_type(4)));

#define NB    64
#define EB    4032            // NB*(NB-1)
#define BATCH 32
#define H     256
#define M_EDGE (BATCH*EB)     // 129024
#define M_NODE (BATCH*NB)     // 2048

// async global->LDS, 16B per lane. LDS dest = wave-uniform base + lane*16B.
__device__ __forceinline__ void load_lds16(const void* g, void* l) {
    __builtin_amdgcn_global_load_lds(
        (const __attribute__((address_space(1))) unsigned int*)g,
        (__attribute__((address_space(3))) unsigned int*)l, 16, 0, 0);
}

// ---------------------------------------------------------------------------
// C[M,256] = ELU(A[M,K] @ W[K,256] + b). Wt = W^T bf16 [256,K].
// TDIM: 128 (edge) or 64 (node) square tile, 4 waves.
// AMODE 0: direct A0. AMODE 1: concat2 gather [send|recv] from A0 (pre-BN-applied).
// AMODE 2: concat3 [send|recv from A0 (pre-applied) | skip from A1 with scA affine].
// STATS: per-column sum/sumsq of post-ELU output -> stats (LDS-reduced, then atomics).
// LDS layout: no pad (stride 32 bf16) as required by global_load_lds lane mapping.
// ---------------------------------------------------------------------------
template<int TDIM, int AMODE, bool STATS, bool AF32>
__global__ __launch_bounds__(256)
void gemm_elu(const void* __restrict__ A0v, const bf16_t* __restrict__ A1,
              const bf16_t* __restrict__ Wt, const float* __restrict__ bias,
              const float* __restrict__ scA,
              bf16_t* __restrict__ out, float* __restrict__ stats, int K)
{
    constexpr int F = TDIM / 32;   // MFMA frags per wave dim
    constexpr int P = TDIM / 64;   // staging passes (64 rows per pass)
    const int m0 = blockIdx.x * TDIM;
    const int n0 = blockIdx.y * TDIM;
    const int tid  = threadIdx.x;
    const int wave = tid >> 6, lane = tid & 63;
    const int wr = wave >> 1, wc = wave & 1;
    const int l15 = lane & 15, quad = lane >> 4;
    const int ch8 = (tid & 3) * 8;

    __shared__ bf16_t smem[TDIM * 64];     // As | Bs, reused as epilogue transpose buf
    bf16_t* As = smem;
    bf16_t* Bs = smem + TDIM * 32;
    __shared__ float sSum[STATS ? TDIM : 1];
    __shared__ float sSq [STATS ? TDIM : 1];
    if (STATS && tid < TDIM) { sSum[tid] = 0.f; sSq[tid] = 0.f; }

    int rowl[P], sndOff[P], rcvOff[P];
#pragma unroll
    for (int p = 0; p < P; ++p) {
        int slot = p * 256 + tid;
        rowl[p] = slot >> 2;
        if (AMODE != 0) {
            int m  = m0 + rowl[p];
            int bb = m / EB;  int e  = m - bb * EB;
            int sn = e / (NB - 1); int rr = e - sn * (NB - 1);
            int rc = rr + (rr >= sn ? 1 : 0);
            sndOff[p] = (bb * NB + sn) * H;
            rcvOff[p] = (bb * NB + rc) * H;
        }
    }

    f32x4 acc[F][F];
#pragma unroll
    for (int t = 0; t < F; ++t)
#pragma unroll
        for (int u = 0; u < F; ++u) acc[t][u] = (f32x4){0.f, 0.f, 0.f, 0.f};

    const bf16_t* A0 = (const bf16_t*)A0v;

    for (int k0 = 0; k0 < K; k0 += 32) {
#pragma unroll
        for (int p = 0; p < P; ++p) {
            bf16_t* ldsA = As + (p * 256 + wave * 64) * 8;   // wave-uniform
            bf16_t* ldsB = Bs + (p * 256 + wave * 64) * 8;
            if (AF32) {
                const float* af = (const float*)A0v + (size_t)(m0 + rowl[p]) * K + k0 + ch8;
                float4 lo = *(const float4*)af;
                float4 hi = *(const float4*)(af + 4);
                bf16x8 v;
                v[0]=(bf16_t)lo.x; v[1]=(bf16_t)lo.y; v[2]=(bf16_t)lo.z; v[3]=(bf16_t)lo.w;
                v[4]=(bf16_t)hi.x; v[5]=(bf16_t)hi.y; v[6]=(bf16_t)hi.z; v[7]=(bf16_t)hi.w;
                *(bf16x8*)&As[rowl[p] * 32 + ch8] = v;
            } else if (AMODE == 0) {
                load_lds16(A0 + (size_t)(m0 + rowl[p]) * K + k0 + ch8, ldsA);
            } else if (AMODE == 1) {
                const bf16_t* src = (k0 < H) ? (A0 + sndOff[p] + k0 + ch8)
                                             : (A0 + rcvOff[p] + (k0 - H) + ch8);
                load_lds16(src, ldsA);
            } else {
                if (k0 < H)          load_lds16(A0 + sndOff[p] + k0 + ch8, ldsA);
                else if (k0 < 2*H)   load_lds16(A0 + rcvOff[p] + (k0 - H) + ch8, ldsA);
                else {
                    int kk = k0 - 2 * H + ch8;
                    bf16x8 v = *(const bf16x8*)(A1 + (size_t)(m0 + rowl[p]) * H + kk);
                    bf16x8 w;
#pragma unroll
                    for (int j = 0; j < 8; ++j)
                        w[j] = (bf16_t)((float)v[j] * scA[kk + j] + scA[H + kk + j]);
                    *(bf16x8*)&As[rowl[p] * 32 + ch8] = w;
                }
            }
            load_lds16(Wt + (size_t)(n0 + rowl[p]) * K + k0 + ch8, ldsB);
        }
        __syncthreads();

        bf16x8 afr[F], bfr[F];
#pragma unroll
        for (int t = 0; t < F; ++t)
            afr[t] = *(const bf16x8*)&As[(wr * (TDIM/2) + t * 16 + l15) * 32 + quad * 8];
#pragma unroll
        for (int u = 0; u < F; ++u)
            bfr[u] = *(const bf16x8*)&Bs[(wc * (TDIM/2) + u * 16 + l15) * 32 + quad * 8];
#pragma unroll
        for (int t = 0; t < F; ++t)
#pragma unroll
            for (int u = 0; u < F; ++u)
                acc[t][u] = __builtin_amdgcn_mfma_f32_16x16x32_bf16(afr[t], bfr[u], acc[t][u], 0, 0, 0);
        __syncthreads();
    }

    // bias + ELU into registers; LDS-reduced BN stats
    bf16_t vals[F][F][4];
#pragma unroll
    for (int u = 0; u < F; ++u) {
        int   col = n0 + wc * (TDIM/2) + u * 16 + l15;
        float bv  = bias[col];
        float s = 0.f, q = 0.f;
#pragma unroll
        for (int t = 0; t < F; ++t)
#pragma unroll
            for (int r = 0; r < 4; ++r) {
                float v = acc[t][u][r] + bv;
                v = v > 0.f ? v : expm1f(v);
                vals[t][u][r] = (bf16_t)v;
                if (STATS) { s += v; q += v * v; }
            }
        if (STATS) {
            s += __shfl_xor(s, 16); s += __shfl_xor(s, 32);
            q += __shfl_xor(q, 16); q += __shfl_xor(q, 32);
            if (quad == 0) {
                int lc = wc * (TDIM/2) + u * 16 + l15;
                atomicAdd(&sSum[lc], s);
                atomicAdd(&sSq[lc], q);
            }
        }
    }

    // transpose through LDS -> coalesced 16B row-major stores
#pragma unroll
    for (int half = 0; half < P; ++half) {
        __syncthreads();
        if (P == 1 || wr == half) {
#pragma unroll
            for (int t = 0; t < F; ++t) {
                int lr = (P == 2 ? 0 : wr * 32) + t * 16 + quad * 4;
#pragma unroll
                for (int u = 0; u < F; ++u) {
                    int lc = wc * (TDIM/2) + u * 16 + l15;
#pragma unroll
                    for (int r = 0; r < 4; ++r)
                        smem[(lr + r) * TDIM + lc] = vals[t][u][r];
                }
            }
        }
        __syncthreads();
#pragma unroll
        for (int sdx = 0; sdx < TDIM/32; ++sdx) {
            int idx = sdx * 256 + tid;
            int lr = idx / (TDIM/8), ch = idx % (TDIM/8);
            *(uint4*)&out[(size_t)(m0 + half * 64 + lr) * H + n0 + ch * 8] =
                *(const uint4*)&smem[lr * TDIM + ch * 8];
        }
    }

    if (STATS) {
        __syncthreads();
        if (tid < TDIM) {
            atomicAdd(&stats[n0 + tid],     sSum[tid]);
            atomicAdd(&stats[H + n0 + tid], sSq[tid]);
        }
    }
}

// ---------------------------------------------------------------------------
__global__ void zero_stats(float* s) { s[blockIdx.x * 256 + threadIdx.x] = 0.f; }

// w[K,256] fp32 -> wt[256,K] bf16
__global__ void transpose_w(const float* __restrict__ w, bf16_t* __restrict__ wt, int K)
{
    int idx = blockIdx.x * 256 + threadIdx.x;
    int k = idx >> 8, n = idx & 255;
    wt[n * K + k] = (bf16_t)w[idx];
}

__global__ void bn_finalize(const float* __restrict__ stats,
                            const float* __restrict__ g, const float* __restrict__ beta,
                            float M, float* __restrict__ sc)
{
    int c = threadIdx.x;
    float mean = stats[c] / M;
    float var  = stats[H + c] / M - mean * mean;
    float scale = g[c] * rsqrtf(var + 1e-5f);
    sc[c]     = scale;
    sc[H + c] = beta[c] - mean * scale;
}

// out-of-place y = x*scale + shift (node tensors only, 1 MB)
__global__ void bn_apply(const bf16_t* __restrict__ x, bf16_t* __restrict__ y,
                         const float* __restrict__ sc, int nvec)
{
    int i = blockIdx.x * 256 + threadIdx.x;
    if (i >= nvec) return;
    bf16x8 v = ((const bf16x8*)x)[i];
    int cb = (i * 8) & 255;
    bf16x8 w;
#pragma unroll
    for (int j = 0; j < 8; ++j)
        w[j] = (bf16_t)((float)v[j] * sc[cb + j] + sc[H + cb + j]);
    ((bf16x8*)y)[i] = w;
}

// inc[b,n,:] = scale*(sum_recv h2)/64 + shift*63/64  (BN2 folded)
__global__ void edge2node(const bf16_t* __restrict__ x2, const float* __restrict__ sc,
                          bf16_t* __restrict__ inc)
{
    int bn = blockIdx.x, bb = bn >> 6, n = bn & 63;
    int g = threadIdx.x >> 5, t = threadIdx.x & 31;
    __shared__ float part[8][256];
    const bf16_t* base = x2 + (size_t)bb * EB * H;
    float a[8] = {0.f,0.f,0.f,0.f,0.f,0.f,0.f,0.f};
    for (int i = g; i < NB; i += 8) {
        if (i == n) continue;
        int e = i * (NB - 1) + n - (n > i ? 1 : 0);
        bf16x8 v = *(const bf16x8*)&base[(size_t)e * H + t * 8];
#pragma unroll
        for (int j = 0; j < 8; ++j) a[j] += (float)v[j];
    }
#pragma unroll
    for (int j = 0; j < 8; ++j) part[g][t * 8 + j] = a[j];
    __syncthreads();
    int c = threadIdx.x;
    float s = 0.f;
#pragma unroll
    for (int g2 = 0; g2 < 8; ++g2) s += part[g2][c];
    inc[(size_t)bn * H + c] = (bf16_t)(s * (1.f / 64.f) * sc[c] + sc[H + c] * (63.f / 64.f));
}

// out[m,0:2] = (h4[m,:]*scale+shift) @ fc_w + fc_b (BN4 folded), fp32 out
__global__ void fc_kernel(const bf16_t* __restrict__ x4, const float* __restrict__ sc,
                          const float* __restrict__ fcw, const float* __restrict__ fcb,
                          float* __restrict__ out)
{
    int row  = blockIdx.x * 8 + (threadIdx.x >> 5);
    int t    = threadIdx.x & 31;
    bf16x8 v8 = *(const bf16x8*)(x4 + (size_t)row * H + t * 8);
    float s0 = 0.f, s1 = 0.f;
#pragma unroll
    for (int j = 0; j < 8; ++j) {
        int c = t * 8 + j;
        float v = (float)v8[j] * sc[c] + sc[H + c];
        s0 += v * fcw[c * 2];
        s1 += v * fcw[c * 2 + 1];
    }
#pragma unroll
    for (int off = 16; off; off >>= 1) {
        s0 += __shfl_down(s0, off, 32);
        s1 += __shfl_down(s1, off, 32);
    }
    if (t == 0) {
        out[(size_t)row * 2]     = s0 + fcb[0];
        out[(size_t)row * 2 + 1] = s1 + fcb[1];
    }
}

// ---------------------------------------------------------------------------
extern "C" void kernel_launch(void* const* d_in, const int* in_sizes, int n_in,
                              void* d_out, int out_size, void* d_ws, size_t ws_size,
                              hipStream_t stream)
{
    (void)in_sizes; (void)n_in; (void)out_size; (void)ws_size;
    const float* inp = (const float*)d_in[0];
    const float* w1a = (const float*)d_in[3];  const float* b1a = (const float*)d_in[4];
    const float* w1b = (const float*)d_in[5];  const float* b1b = (const float*)d_in[6];
    const float* g1  = (const float*)d_in[7];  const float* be1 = (const float*)d_in[8];
    const float* w2a = (const float*)d_in[9];  const float* b2a = (const float*)d_in[10];
    const float* w2b = (const float*)d_in[11]; const float* b2b = (const float*)d_in[12];
    const float* g2  = (const float*)d_in[13]; const float* be2 = (const float*)d_in[14];
    const float* w3a = (const float*)d_in[15]; const float* b3a = (const float*)d_in[16];
    const float* w3b = (const float*)d_in[17]; const float* b3b = (const float*)d_in[18];
    const float* g3  = (const float*)d_in[19]; const float* be3 = (const float*)d_in[20];
    const float* w4a = (const float*)d_in[21]; const float* b4a = (const float*)d_in[22];
    const float* w4b = (const float*)d_in[23]; const float* b4b = (const float*)d_in[24];
    const float* g4  = (const float*)d_in[25]; const float* be4 = (const float*)d_in[26];
    const float* fcw = (const float*)d_in[27]; const float* fcb = (const float*)d_in[28];

    char* p = (char*)d_ws;
    auto alloc = [&](size_t nbytes) { char* r = p; p += (nbytes + 255) & ~(size_t)255; return r; };

    bf16_t* wt1a = (bf16_t*)alloc(256 * 256 * 2);
    bf16_t* wt1b = (bf16_t*)alloc(256 * 256 * 2);
    bf16_t* wt2a = (bf16_t*)alloc(512 * 256 * 2);
    bf16_t* wt2b = (bf16_t*)alloc(256 * 256 * 2);
    bf16_t* wt3a = (bf16_t*)alloc(256 * 256 * 2);
    bf16_t* wt3b = (bf16_t*)alloc(256 * 256 * 2);
    bf16_t* wt4a = (bf16_t*)alloc(768 * 256 * 2);
    bf16_t* wt4b = (bf16_t*)alloc(256 * 256 * 2);
    float*  stats = (float*)alloc(4 * 512 * sizeof(float));
    float*  sc    = (float*)alloc(4 * 512 * sizeof(float));
    bf16_t* hn   = (bf16_t*)alloc((size_t)M_NODE * H * 2);
    bf16_t* x1   = (bf16_t*)alloc((size_t)M_NODE * H * 2);
    bf16_t* x1bn = (bf16_t*)alloc((size_t)M_NODE * H * 2);
    bf16_t* incb = (bf16_t*)alloc((size_t)M_NODE * H * 2);
    bf16_t* x3   = (bf16_t*)alloc((size_t)M_NODE * H * 2);
    bf16_t* x3bn = (bf16_t*)alloc((size_t)M_NODE * H * 2);
    bf16_t* bufA = (bf16_t*)alloc((size_t)M_EDGE * H * 2);
    bf16_t* bufB = (bf16_t*)alloc((size_t)M_EDGE * H * 2);

    zero_stats<<<8, 256, 0, stream>>>(stats);
    transpose_w<<<256, 256, 0, stream>>>(w1a, wt1a, 256);
    transpose_w<<<256, 256, 0, stream>>>(w1b, wt1b, 256);
    transpose_w<<<512, 256, 0, stream>>>(w2a, wt2a, 512);
    transpose_w<<<256, 256, 0, stream>>>(w2b, wt2b, 256);
    transpose_w<<<256, 256, 0, stream>>>(w3a, wt3a, 256);
    transpose_w<<<256, 256, 0, stream>>>(w3b, wt3b, 256);
    transpose_w<<<768, 256, 0, stream>>>(w4a, wt4a, 768);
    transpose_w<<<256, 256, 0, stream>>>(w4b, wt4b, 256);

    dim3 gN(M_NODE / 64, 4), gE(M_EDGE / 128, 2);

    // MLP1 (nodes, 64-tiles)
    gemm_elu<64, 0, false, true ><<<gN, 256, 0, stream>>>(inp, nullptr, wt1a, b1a, nullptr, hn, nullptr, 256);
    gemm_elu<64, 0, true,  false><<<gN, 256, 0, stream>>>(hn,  nullptr, wt1b, b1b, nullptr, x1, stats + 0, 256);
    bn_finalize<<<1, 256, 0, stream>>>(stats + 0, g1, be1, (float)M_NODE, sc + 0);
    bn_apply<<<M_NODE * H / 8 / 256, 256, 0, stream>>>(x1, x1bn, sc + 0, M_NODE * H / 8);

    // MLP2 (edges, concat[send,recv] from x1bn)
    gemm_elu<128, 1, false, false><<<gE, 256, 0, stream>>>(x1bn, nullptr, wt2a, b2a, nullptr, bufA, nullptr, 512);
    gemm_elu<128, 0, true,  false><<<gE, 256, 0, stream>>>(bufA, nullptr, wt2b, b2b, nullptr, bufB, stats + 512, 256);
    bn_finalize<<<1, 256, 0, stream>>>(stats + 512, g2, be2, (float)M_EDGE, sc + 512);
    // bufB = h2 raw; BN2 (sc+512) folded into consumers

    // edge2node (BN2 folded) + MLP3 (nodes)
    edge2node<<<M_NODE, 256, 0, stream>>>(bufB, sc + 512, incb);
    gemm_elu<64, 0, false, false><<<gN, 256, 0, stream>>>(incb, nullptr, wt3a, b3a, nullptr, hn, nullptr, 256);
    gemm_elu<64, 0, true,  false><<<gN, 256, 0, stream>>>(hn,   nullptr, wt3b, b3b, nullptr, x3, stats + 1024, 256);
    bn_finalize<<<1, 256, 0, stream>>>(stats + 1024, g3, be3, (float)M_NODE, sc + 1024);
    bn_apply<<<M_NODE * H / 8 / 256, 256, 0, stream>>>(x3, x3bn, sc + 1024, M_NODE * H / 8);

    // MLP4 (edges, concat[send,recv from x3bn | skip = BN2(h2) inline])
    gemm_elu<128, 2, false, false><<<gE, 256, 0, stream>>>(x3bn, bufB, wt4a, b4a, sc + 512, bufA, nullptr, 768);
    gemm_elu<128, 0, true,  false><<<gE, 256, 0, stream>>>(bufA, nullptr, wt4b, b4b, nullptr, bufB, stats + 1536, 256);
    bn_finalize<<<1, 256, 0, stream>>>(stats + 1536, g4, be4, (float)M_EDGE, sc + 1536);

    // final fc with BN4 folded, fp32 output
    fc_kernel<<<M_EDGE / 8, 256, 0, stream>>>(bufB, sc + 1536, fcw, fcb, (float*)d_out);
}

// Round 4
// 510.172 us; speedup vs baseline: 1.3238x; 1.0035x over previous
//
#include <hip/hip_runtime.h>

typedef __bf16 bf16_t;
typedef __bf16 bf16x8 __attribute__((ext_vector_type(8)));
typedef float  f32x4  __attribute__((ext_vector_type(4)));

#define NB    64
#define EB    4032            // NB*(NB-1)
#define BATCH 32
#define H     256
#define M_EDGE (BATCH*EB)     // 129024
#define M_NODE (BATCH*NB)     // 2048

// async global->LDS, 16B per lane. LDS dest = wave-uniform base + lane*16B.
__device__ __forceinline__ void load_lds16(const void* g, void* l) {
    __builtin_amdgcn_global_load_lds(
        (const __attribute__((address_space(1))) unsigned int*)g,
        (__attribute__((address_space(3))) unsigned int*)l, 16, 0, 0);
}

// ---------------------------------------------------------------------------
// C[M,256] = ELU(A[M,K] @ W[K,256] + b). Wt = W^T bf16 [256,K].
// TDIM: 128 (edge) or 64 (node) square tile, 4 waves.
// AMODE 0: direct A0. AMODE 1: concat2 gather [send|recv]. AMODE 2: concat3
//   [send|recv | skip from A1 with scA affine]. STATS: BN sum/sumsq.
// LDS: no pad (stride 32 bf16, global_load_lds requirement) + XOR chunk swizzle:
//   slot s of row R holds chunk s ^ ((R>>1)&3)  -> ds_read_b128 2-way (free)
//   instead of 8-way (2.94x) bank conflicts.
// ---------------------------------------------------------------------------
template<int TDIM, int AMODE, bool STATS, bool AF32>
__global__ __launch_bounds__(256)
void gemm_elu(const void* __restrict__ A0v, const bf16_t* __restrict__ A1,
              const bf16_t* __restrict__ Wt, const float* __restrict__ bias,
              const float* __restrict__ scA,
              bf16_t* __restrict__ out, float* __restrict__ stats, int K)
{
    constexpr int F = TDIM / 32;   // MFMA frags per wave dim
    constexpr int P = TDIM / 64;   // staging passes (64 rows per pass)
    const int m0 = blockIdx.x * TDIM;
    const int n0 = blockIdx.y * TDIM;
    const int tid  = threadIdx.x;
    const int wave = tid >> 6, lane = tid & 63;
    const int wr = wave >> 1, wc = wave & 1;
    const int l15 = lane & 15, quad = lane >> 4;
    // staging: lane's LDS slot is (tid&3); it fetches chunk (tid&3)^((row>>1)&3)
    const int cx8 = (((tid & 3) ^ ((tid >> 3) & 3))) * 8;   // row = tid>>2 (+64p: same xor)
    const int sl8 = (tid & 3) * 8;
    // read: chunk quad of row R lives in slot quad^((R>>1)&3); R base mult of 16
    const int xq8 = (quad ^ ((l15 >> 1) & 3)) * 8;

    __shared__ bf16_t smem[TDIM * 64];     // As | Bs, reused as epilogue transpose buf
    bf16_t* As = smem;
    bf16_t* Bs = smem + TDIM * 32;
    __shared__ float sSum[STATS ? TDIM : 1];
    __shared__ float sSq [STATS ? TDIM : 1];
    if (STATS && tid < TDIM) { sSum[tid] = 0.f; sSq[tid] = 0.f; }

    int rowl[P], sndOff[P], rcvOff[P];
#pragma unroll
    for (int p = 0; p < P; ++p) {
        int slot = p * 256 + tid;
        rowl[p] = slot >> 2;
        if (AMODE != 0) {
            int m  = m0 + rowl[p];
            int bb = m / EB;  int e  = m - bb * EB;
            int sn = e / (NB - 1); int rr = e - sn * (NB - 1);
            int rc = rr + (rr >= sn ? 1 : 0);
            sndOff[p] = (bb * NB + sn) * H;
            rcvOff[p] = (bb * NB + rc) * H;
        }
    }

    f32x4 acc[F][F];
#pragma unroll
    for (int t = 0; t < F; ++t)
#pragma unroll
        for (int u = 0; u < F; ++u) acc[t][u] = (f32x4){0.f, 0.f, 0.f, 0.f};

    const bf16_t* A0 = (const bf16_t*)A0v;

    for (int k0 = 0; k0 < K; k0 += 32) {
#pragma unroll
        for (int p = 0; p < P; ++p) {
            bf16_t* ldsA = As + (p * 256 + wave * 64) * 8;   // wave-uniform
            bf16_t* ldsB = Bs + (p * 256 + wave * 64) * 8;
            if (AF32) {
                const float* af = (const float*)A0v + (size_t)(m0 + rowl[p]) * K + k0 + cx8;
                float4 lo = *(const float4*)af;
                float4 hi = *(const float4*)(af + 4);
                bf16x8 v;
                v[0]=(bf16_t)lo.x; v[1]=(bf16_t)lo.y; v[2]=(bf16_t)lo.z; v[3]=(bf16_t)lo.w;
                v[4]=(bf16_t)hi.x; v[5]=(bf16_t)hi.y; v[6]=(bf16_t)hi.z; v[7]=(bf16_t)hi.w;
                *(bf16x8*)&As[rowl[p] * 32 + sl8] = v;
            } else if (AMODE == 0) {
                load_lds16(A0 + (size_t)(m0 + rowl[p]) * K + k0 + cx8, ldsA);
            } else if (AMODE == 1) {
                const bf16_t* src = (k0 < H) ? (A0 + sndOff[p] + k0 + cx8)
                                             : (A0 + rcvOff[p] + (k0 - H) + cx8);
                load_lds16(src, ldsA);
            } else {
                if (k0 < H)          load_lds16(A0 + sndOff[p] + k0 + cx8, ldsA);
                else if (k0 < 2*H)   load_lds16(A0 + rcvOff[p] + (k0 - H) + cx8, ldsA);
                else {
                    int kk = k0 - 2 * H + cx8;
                    bf16x8 v = *(const bf16x8*)(A1 + (size_t)(m0 + rowl[p]) * H + kk);
                    bf16x8 w;
#pragma unroll
                    for (int j = 0; j < 8; ++j)
                        w[j] = (bf16_t)((float)v[j] * scA[kk + j] + scA[H + kk + j]);
                    *(bf16x8*)&As[rowl[p] * 32 + sl8] = w;
                }
            }
            load_lds16(Wt + (size_t)(n0 + rowl[p]) * K + k0 + cx8, ldsB);
        }
        __syncthreads();

        bf16x8 afr[F], bfr[F];
#pragma unroll
        for (int t = 0; t < F; ++t)
            afr[t] = *(const bf16x8*)&As[(wr * (TDIM/2) + t * 16 + l15) * 32 + xq8];
#pragma unroll
        for (int u = 0; u < F; ++u)
            bfr[u] = *(const bf16x8*)&Bs[(wc * (TDIM/2) + u * 16 + l15) * 32 + xq8];
#pragma unroll
        for (int t = 0; t < F; ++t)
#pragma unroll
            for (int u = 0; u < F; ++u)
                acc[t][u] = __builtin_amdgcn_mfma_f32_16x16x32_bf16(afr[t], bfr[u], acc[t][u], 0, 0, 0);
        __syncthreads();
    }

    // bias + ELU into registers; LDS-reduced BN stats
    bf16_t vals[F][F][4];
#pragma unroll
    for (int u = 0; u < F; ++u) {
        int   col = n0 + wc * (TDIM/2) + u * 16 + l15;
        float bv  = bias[col];
        float s = 0.f, q = 0.f;
#pragma unroll
        for (int t = 0; t < F; ++t)
#pragma unroll
            for (int r = 0; r < 4; ++r) {
                float v = acc[t][u][r] + bv;
                v = v > 0.f ? v : expm1f(v);
                vals[t][u][r] = (bf16_t)v;
                if (STATS) { s += v; q += v * v; }
            }
        if (STATS) {
            s += __shfl_xor(s, 16); s += __shfl_xor(s, 32);
            q += __shfl_xor(q, 16); q += __shfl_xor(q, 32);
            if (quad == 0) {
                int lc = wc * (TDIM/2) + u * 16 + l15;
                atomicAdd(&sSum[lc], s);
                atomicAdd(&sSq[lc], q);
            }
        }
    }

    // transpose through LDS -> coalesced 16B row-major stores
#pragma unroll
    for (int half = 0; half < P; ++half) {
        __syncthreads();
        if (P == 1 || wr == half) {
#pragma unroll
            for (int t = 0; t < F; ++t) {
                int lr = (P == 2 ? 0 : wr * 32) + t * 16 + quad * 4;
#pragma unroll
                for (int u = 0; u < F; ++u) {
                    int lc = wc * (TDIM/2) + u * 16 + l15;
#pragma unroll
                    for (int r = 0; r < 4; ++r)
                        smem[(lr + r) * TDIM + lc] = vals[t][u][r];
                }
            }
        }
        __syncthreads();
#pragma unroll
        for (int sdx = 0; sdx < TDIM/32; ++sdx) {
            int idx = sdx * 256 + tid;
            int lr = idx / (TDIM/8), ch = idx % (TDIM/8);
            *(uint4*)&out[(size_t)(m0 + half * 64 + lr) * H + n0 + ch * 8] =
                *(const uint4*)&smem[lr * TDIM + ch * 8];
        }
    }

    if (STATS) {
        __syncthreads();
        if (tid < TDIM) {
            atomicAdd(&stats[n0 + tid],     sSum[tid]);
            atomicAdd(&stats[H + n0 + tid], sSq[tid]);
        }
    }
}

// ---------------------------------------------------------------------------
__global__ void zero_stats(float* s) { s[blockIdx.x * 256 + threadIdx.x] = 0.f; }

// w[K,256] fp32 -> wt[256,K] bf16
__global__ void transpose_w(const float* __restrict__ w, bf16_t* __restrict__ wt, int K)
{
    int idx = blockIdx.x * 256 + threadIdx.x;
    int k = idx >> 8, n = idx & 255;
    wt[n * K + k] = (bf16_t)w[idx];
}

__global__ void bn_finalize(const float* __restrict__ stats,
                            const float* __restrict__ g, const float* __restrict__ beta,
                            float M, float* __restrict__ sc)
{
    int c = threadIdx.x;
    float mean = stats[c] / M;
    float var  = stats[H + c] / M - mean * mean;
    float scale = g[c] * rsqrtf(var + 1e-5f);
    sc[c]     = scale;
    sc[H + c] = beta[c] - mean * scale;
}

// out-of-place y = x*scale + shift (node tensors only, 1 MB)
__global__ void bn_apply(const bf16_t* __restrict__ x, bf16_t* __restrict__ y,
                         const float* __restrict__ sc, int nvec)
{
    int i = blockIdx.x * 256 + threadIdx.x;
    if (i >= nvec) return;
    bf16x8 v = ((const bf16x8*)x)[i];
    int cb = (i * 8) & 255;
    bf16x8 w;
#pragma unroll
    for (int j = 0; j < 8; ++j)
        w[j] = (bf16_t)((float)v[j] * sc[cb + j] + sc[H + cb + j]);
    ((bf16x8*)y)[i] = w;
}

// inc[b,n,:] = scale*(sum_recv h2)/64 + shift*63/64  (BN2 folded)
__global__ void edge2node(const bf16_t* __restrict__ x2, const float* __restrict__ sc,
                          bf16_t* __restrict__ inc)
{
    int bn = blockIdx.x, bb = bn >> 6, n = bn & 63;
    int g = threadIdx.x >> 5, t = threadIdx.x & 31;
    __shared__ float part[8][256];
    const bf16_t* base = x2 + (size_t)bb * EB * H;
    float a[8] = {0.f,0.f,0.f,0.f,0.f,0.f,0.f,0.f};
    for (int i = g; i < NB; i += 8) {
        if (i == n) continue;
        int e = i * (NB - 1) + n - (n > i ? 1 : 0);
        bf16x8 v = *(const bf16x8*)&base[(size_t)e * H + t * 8];
#pragma unroll
        for (int j = 0; j < 8; ++j) a[j] += (float)v[j];
    }
#pragma unroll
    for (int j = 0; j < 8; ++j) part[g][t * 8 + j] = a[j];
    __syncthreads();
    int c = threadIdx.x;
    float s = 0.f;
#pragma unroll
    for (int g2 = 0; g2 < 8; ++g2) s += part[g2][c];
    inc[(size_t)bn * H + c] = (bf16_t)(s * (1.f / 64.f) * sc[c] + sc[H + c] * (63.f / 64.f));
}

// out[m,0:2] = (h4[m,:]*scale+shift) @ fc_w + fc_b (BN4 folded), fp32 out
__global__ void fc_kernel(const bf16_t* __restrict__ x4, const float* __restrict__ sc,
                          const float* __restrict__ fcw, const float* __restrict__ fcb,
                          float* __restrict__ out)
{
    int row  = blockIdx.x * 8 + (threadIdx.x >> 5);
    int t    = threadIdx.x & 31;
    bf16x8 v8 = *(const bf16x8*)(x4 + (size_t)row * H + t * 8);
    float s0 = 0.f, s1 = 0.f;
#pragma unroll
    for (int j = 0; j < 8; ++j) {
        int c = t * 8 + j;
        float v = (float)v8[j] * sc[c] + sc[H + c];
        s0 += v * fcw[c * 2];
        s1 += v * fcw[c * 2 + 1];
    }
#pragma unroll
    for (int off = 16; off; off >>= 1) {
        s0 += __shfl_down(s0, off, 32);
        s1 += __shfl_down(s1, off, 32);
    }
    if (t == 0) {
        out[(size_t)row * 2]     = s0 + fcb[0];
        out[(size_t)row * 2 + 1] = s1 + fcb[1];
    }
}

// ---------------------------------------------------------------------------
extern "C" void kernel_launch(void* const* d_in, const int* in_sizes, int n_in,
                              void* d_out, int out_size, void* d_ws, size_t ws_size,
                              hipStream_t stream)
{
    (void)in_sizes; (void)n_in; (void)out_size; (void)ws_size;
    const float* inp = (const float*)d_in[0];
    const float* w1a = (const float*)d_in[3];  const float* b1a = (const float*)d_in[4];
    const float* w1b = (const float*)d_in[5];  const float* b1b = (const float*)d_in[6];
    const float* g1  = (const float*)d_in[7];  const float* be1 = (const float*)d_in[8];
    const float* w2a = (const float*)d_in[9];  const float* b2a = (const float*)d_in[10];
    const float* w2b = (const float*)d_in[11]; const float* b2b = (const float*)d_in[12];
    const float* g2  = (const float*)d_in[13]; const float* be2 = (const float*)d_in[14];
    const float* w3a = (const float*)d_in[15]; const float* b3a = (const float*)d_in[16];
    const float* w3b = (const float*)d_in[17]; const float* b3b = (const float*)d_in[18];
    const float* g3  = (const float*)d_in[19]; const float* be3 = (const float*)d_in[20];
    const float* w4a = (const float*)d_in[21]; const float* b4a = (const float*)d_in[22];
    const float* w4b = (const float*)d_in[23]; const float* b4b = (const float*)d_in[24];
    const float* g4  = (const float*)d_in[25]; const float* be4 = (const float*)d_in[26];
    const float* fcw = (const float*)d_in[27]; const float* fcb = (const float*)d_in[28];

    char* p = (char*)d_ws;
    auto alloc = [&](size_t nbytes) { char* r = p; p += (nbytes + 255) & ~(size_t)255; return r; };

    bf16_t* wt1a = (bf16_t*)alloc(256 * 256 * 2);
    bf16_t* wt1b = (bf16_t*)alloc(256 * 256 * 2);
    bf16_t* wt2a = (bf16_t*)alloc(512 * 256 * 2);
    bf16_t* wt2b = (bf16_t*)alloc(256 * 256 * 2);
    bf16_t* wt3a = (bf16_t*)alloc(256 * 256 * 2);
    bf16_t* wt3b = (bf16_t*)alloc(256 * 256 * 2);
    bf16_t* wt4a = (bf16_t*)alloc(768 * 256 * 2);
    bf16_t* wt4b = (bf16_t*)alloc(256 * 256 * 2);
    float*  stats = (float*)alloc(4 * 512 * sizeof(float));
    float*  sc    = (float*)alloc(4 * 512 * sizeof(float));
    bf16_t* hn   = (bf16_t*)alloc((size_t)M_NODE * H * 2);
    bf16_t* x1   = (bf16_t*)alloc((size_t)M_NODE * H * 2);
    bf16_t* x1bn = (bf16_t*)alloc((size_t)M_NODE * H * 2);
    bf16_t* incb = (bf16_t*)alloc((size_t)M_NODE * H * 2);
    bf16_t* x3   = (bf16_t*)alloc((size_t)M_NODE * H * 2);
    bf16_t* x3bn = (bf16_t*)alloc((size_t)M_NODE * H * 2);
    bf16_t* bufA = (bf16_t*)alloc((size_t)M_EDGE * H * 2);
    bf16_t* bufB = (bf16_t*)alloc((size_t)M_EDGE * H * 2);

    zero_stats<<<8, 256, 0, stream>>>(stats);
    transpose_w<<<256, 256, 0, stream>>>(w1a, wt1a, 256);
    transpose_w<<<256, 256, 0, stream>>>(w1b, wt1b, 256);
    transpose_w<<<512, 256, 0, stream>>>(w2a, wt2a, 512);
    transpose_w<<<256, 256, 0, stream>>>(w2b, wt2b, 256);
    transpose_w<<<256, 256, 0, stream>>>(w3a, wt3a, 256);
    transpose_w<<<256, 256, 0, stream>>>(w3b, wt3b, 256);
    transpose_w<<<768, 256, 0, stream>>>(w4a, wt4a, 768);
    transpose_w<<<256, 256, 0, stream>>>(w4b, wt4b, 256);

    dim3 gN(M_NODE / 64, 4), gE(M_EDGE / 128, 2);

    // MLP1 (nodes, 64-tiles)
    gemm_elu<64, 0, false, true ><<<gN, 256, 0, stream>>>(inp, nullptr, wt1a, b1a, nullptr, hn, nullptr, 256);
    gemm_elu<64, 0, true,  false><<<gN, 256, 0, stream>>>(hn,  nullptr, wt1b, b1b, nullptr, x1, stats + 0, 256);
    bn_finalize<<<1, 256, 0, stream>>>(stats + 0, g1, be1, (float)M_NODE, sc + 0);
    bn_apply<<<M_NODE * H / 8 / 256, 256, 0, stream>>>(x1, x1bn, sc + 0, M_NODE * H / 8);

    // MLP2 (edges, concat[send,recv] from x1bn)
    gemm_elu<128, 1, false, false><<<gE, 256, 0, stream>>>(x1bn, nullptr, wt2a, b2a, nullptr, bufA, nullptr, 512);
    gemm_elu<128, 0, true,  false><<<gE, 256, 0, stream>>>(bufA, nullptr, wt2b, b2b, nullptr, bufB, stats + 512, 256);
    bn_finalize<<<1, 256, 0, stream>>>(stats + 512, g2, be2, (float)M_EDGE, sc + 512);
    // bufB = h2 raw; BN2 (sc+512) folded into consumers

    // edge2node (BN2 folded) + MLP3 (nodes)
    edge2node<<<M_NODE, 256, 0, stream>>>(bufB, sc + 512, incb);
    gemm_elu<64, 0, false, false><<<gN, 256, 0, stream>>>(incb, nullptr, wt3a, b3a, nullptr, hn, nullptr, 256);
    gemm_elu<64, 0, true,  false><<<gN, 256, 0, stream>>>(hn,   nullptr, wt3b, b3b, nullptr, x3, stats + 1024, 256);
    bn_finalize<<<1, 256, 0, stream>>>(stats + 1024, g3, be3, (float)M_NODE, sc + 1024);
    bn_apply<<<M_NODE * H / 8 / 256, 256, 0, stream>>>(x3, x3bn, sc + 1024, M_NODE * H / 8);

    // MLP4 (edges, concat[send,recv from x3bn | skip = BN2(h2) inline])
    gemm_elu<128, 2, false, false><<<gE, 256, 0, stream>>>(x3bn, bufB, wt4a, b4a, sc + 512, bufA, nullptr, 768);
    gemm_elu<128, 0, true,  false><<<gE, 256, 0, stream>>>(bufA, nullptr, wt4b, b4b, nullptr, bufB, stats + 1536, 256);
    bn_finalize<<<1, 256, 0, stream>>>(stats + 1536, g4, be4, (float)M_EDGE, sc + 1536);

    // final fc with BN4 folded, fp32 output
    fc_kernel<<<M_EDGE / 8, 256, 0, stream>>>(bufB, sc + 1536, fcw, fcb, (float*)d_out);
}

// Round 5
// 502.797 us; speedup vs baseline: 1.3433x; 1.0147x over previous
//
#include <hip/hip_runtime.h>

typedef __bf16 bf16_t;
typedef __bf16 bf16x8 __attribute__((ext_vector_type(8)));
typedef float  f32x4  __attribute__((ext_vector_type(4)));

#define NB    64
#define EB    4032            // NB*(NB-1)
#define BATCH 32
#define H     256
#define M_EDGE (BATCH*EB)     // 129024
#define M_NODE (BATCH*NB)     // 2048

// async global->LDS, 16B per lane. LDS dest = wave-uniform base + lane*16B.
__device__ __forceinline__ void load_lds16(const void* g, void* l) {
    __builtin_amdgcn_global_load_lds(
        (const __attribute__((address_space(1))) unsigned int*)g,
        (__attribute__((address_space(3))) unsigned int*)l, 16, 0, 0);
}

// ---------------------------------------------------------------------------
// Fused 2-layer MLP tile: out = ELU( ELU(A@W1+b1) @ W2 + b2 ), 64 rows x 256 cols.
// L1: K1 loop, A staged via global_load_lds (or gather/cvt), W1t tile staged.
// h1 (64x256) kept in LDS; L2: K=256 loop reads A-frags from LDS, stages W2t only.
// AMODE 0: direct A0 (AF32: fp32 cvt). 1: concat2 [send|recv]. 2: concat3
//   [send|recv|skip=A1 w/ scA affine]. BN stats (sum/sumsq of final out) always.
// LDS: As aliases h1s[0..2048) (L1 phase only); +XOR chunk swizzle for staging.
// ---------------------------------------------------------------------------
template<int AMODE, bool AF32>
__global__ __launch_bounds__(256)
void fused_mlp(const void* __restrict__ A0v, const bf16_t* __restrict__ A1,
               const bf16_t* __restrict__ W1t, const float* __restrict__ b1,
               const bf16_t* __restrict__ W2t, const float* __restrict__ b2,
               const float* __restrict__ scA,
               bf16_t* __restrict__ out, float* __restrict__ stats, int K1)
{
    const int m0   = blockIdx.x * 64;
    const int tid  = threadIdx.x;
    const int wave = tid >> 6, lane = tid & 63;
    const int l15  = lane & 15, quad = lane >> 4;
    const int row  = tid >> 2;                         // staging row 0..63
    const int cx8  = (((tid & 3) ^ ((tid >> 3) & 3))) * 8;  // fetched chunk (swizzled)
    const int sl8  = (tid & 3) * 8;                    // LDS slot
    const int xq8  = (quad ^ ((l15 >> 1) & 3)) * 8;    // read-side swizzle

    __shared__ bf16_t h1s[64 * 264];   // h1 [64][264 pad] / As alias (L1) / epilogue buf
    __shared__ bf16_t Bs[256 * 32];    // W-tile staging (L1 and L2)
    __shared__ float  sred[512];       // BN stat reduction

    int sndOff = 0, rcvOff = 0;
    if (AMODE != 0) {
        int m  = m0 + row;
        int bb = m / EB;  int e  = m - bb * EB;
        int sn = e / (NB - 1); int rr = e - sn * (NB - 1);
        int rc = rr + (rr >= sn ? 1 : 0);
        sndOff = (bb * NB + sn) * H;
        rcvOff = (bb * NB + rc) * H;
    }

    const bf16_t* A0 = (const bf16_t*)A0v;

    // ---------------- L1: acc1 = A @ W1 ----------------
    f32x4 acc1[4][4];
#pragma unroll
    for (int t = 0; t < 4; ++t)
#pragma unroll
        for (int u = 0; u < 4; ++u) acc1[t][u] = (f32x4){0.f, 0.f, 0.f, 0.f};

    for (int k0 = 0; k0 < K1; k0 += 32) {
        // A tile: 64 rows x 32 k  (one 16B chunk per thread)
        bf16_t* ldsA = h1s + wave * 512;   // wave-uniform base, lane*16B dests
        if (AF32) {
            const float* af = (const float*)A0v + (size_t)(m0 + row) * K1 + k0 + cx8;
            float4 lo = *(const float4*)af;
            float4 hi = *(const float4*)(af + 4);
            bf16x8 v;
            v[0]=(bf16_t)lo.x; v[1]=(bf16_t)lo.y; v[2]=(bf16_t)lo.z; v[3]=(bf16_t)lo.w;
            v[4]=(bf16_t)hi.x; v[5]=(bf16_t)hi.y; v[6]=(bf16_t)hi.z; v[7]=(bf16_t)hi.w;
            *(bf16x8*)&h1s[row * 32 + sl8] = v;
        } else if (AMODE == 0) {
            load_lds16(A0 + (size_t)(m0 + row) * K1 + k0 + cx8, ldsA);
        } else if (AMODE == 1) {
            const bf16_t* src = (k0 < H) ? (A0 + sndOff + k0 + cx8)
                                         : (A0 + rcvOff + (k0 - H) + cx8);
            load_lds16(src, ldsA);
        } else {
            if (k0 < H)          load_lds16(A0 + sndOff + k0 + cx8, ldsA);
            else if (k0 < 2*H)   load_lds16(A0 + rcvOff + (k0 - H) + cx8, ldsA);
            else {
                int kk = k0 - 2 * H + cx8;
                bf16x8 v = *(const bf16x8*)(A1 + (size_t)(m0 + row) * H + kk);
                bf16x8 w;
#pragma unroll
                for (int j = 0; j < 8; ++j)
                    w[j] = (bf16_t)((float)v[j] * scA[kk + j] + scA[H + kk + j]);
                *(bf16x8*)&h1s[row * 32 + sl8] = w;
            }
        }
        // W1 tile: 256 out-cols x 32 k
#pragma unroll
        for (int p = 0; p < 4; ++p)
            load_lds16(W1t + (size_t)(p * 64 + row) * K1 + k0 + cx8,
                       Bs + (p * 256 + wave * 64) * 8);
        __syncthreads();

        bf16x8 afr[4], bfr[4];
#pragma unroll
        for (int t = 0; t < 4; ++t)
            afr[t] = *(const bf16x8*)&h1s[(t * 16 + l15) * 32 + xq8];
#pragma unroll
        for (int u = 0; u < 4; ++u)
            bfr[u] = *(const bf16x8*)&Bs[(wave * 64 + u * 16 + l15) * 32 + xq8];
#pragma unroll
        for (int t = 0; t < 4; ++t)
#pragma unroll
            for (int u = 0; u < 4; ++u)
                acc1[t][u] = __builtin_amdgcn_mfma_f32_16x16x32_bf16(afr[t], bfr[u], acc1[t][u], 0, 0, 0);
        __syncthreads();
    }

    // ---------------- h1 = ELU(acc1+b1) -> LDS [64][264] ----------------
#pragma unroll
    for (int u = 0; u < 4; ++u) {
        int   col = wave * 64 + u * 16 + l15;
        float bv  = b1[col];
#pragma unroll
        for (int t = 0; t < 4; ++t)
#pragma unroll
            for (int r = 0; r < 4; ++r) {
                float v = acc1[t][u][r] + bv;
                v = v > 0.f ? v : expm1f(v);
                h1s[(t * 16 + quad * 4 + r) * 264 + col] = (bf16_t)v;
            }
    }
    sred[tid] = 0.f; sred[256 + tid] = 0.f;
    __syncthreads();

    // ---------------- L2: acc2 = h1 @ W2 (K=256) ----------------
    f32x4 acc2[4][4];
#pragma unroll
    for (int t = 0; t < 4; ++t)
#pragma unroll
        for (int u = 0; u < 4; ++u) acc2[t][u] = (f32x4){0.f, 0.f, 0.f, 0.f};

    for (int k0 = 0; k0 < 256; k0 += 32) {
#pragma unroll
        for (int p = 0; p < 4; ++p)
            load_lds16(W2t + (size_t)(p * 64 + row) * 256 + k0 + cx8,
                       Bs + (p * 256 + wave * 64) * 8);
        __syncthreads();

        bf16x8 afr[4], bfr[4];
#pragma unroll
        for (int t = 0; t < 4; ++t)
            afr[t] = *(const bf16x8*)&h1s[(t * 16 + l15) * 264 + k0 + quad * 8];
#pragma unroll
        for (int u = 0; u < 4; ++u)
            bfr[u] = *(const bf16x8*)&Bs[(wave * 64 + u * 16 + l15) * 32 + xq8];
#pragma unroll
        for (int t = 0; t < 4; ++t)
#pragma unroll
            for (int u = 0; u < 4; ++u)
                acc2[t][u] = __builtin_amdgcn_mfma_f32_16x16x32_bf16(afr[t], bfr[u], acc2[t][u], 0, 0, 0);
        __syncthreads();
    }

    // ---------------- epilogue: ELU + BN stats + coalesced store ----------------
#pragma unroll
    for (int u = 0; u < 4; ++u) {
        int   col = wave * 64 + u * 16 + l15;
        float bv  = b2[col];
        float s = 0.f, q = 0.f;
#pragma unroll
        for (int t = 0; t < 4; ++t)
#pragma unroll
            for (int r = 0; r < 4; ++r) {
                float v = acc2[t][u][r] + bv;
                v = v > 0.f ? v : expm1f(v);
                h1s[(t * 16 + quad * 4 + r) * 264 + col] = (bf16_t)v;
                s += v; q += v * v;
            }
        s += __shfl_xor(s, 16); s += __shfl_xor(s, 32);
        q += __shfl_xor(q, 16); q += __shfl_xor(q, 32);
        if (quad == 0) {
            atomicAdd(&sred[col], s);
            atomicAdd(&sred[256 + col], q);
        }
    }
    __syncthreads();

#pragma unroll
    for (int p = 0; p < 8; ++p) {
        int idx = p * 256 + tid;
        int r = idx >> 5, ch = idx & 31;
        *(uint4*)&out[(size_t)(m0 + r) * H + ch * 8] = *(const uint4*)&h1s[r * 264 + ch * 8];
    }
    atomicAdd(&stats[tid],     sred[tid]);
    atomicAdd(&stats[H + tid], sred[256 + tid]);
}

// ---------------------------------------------------------------------------
__global__ void zero_stats(float* s) { s[blockIdx.x * 256 + threadIdx.x] = 0.f; }

// w[K,256] fp32 -> wt[256,K] bf16
__global__ void transpose_w(const float* __restrict__ w, bf16_t* __restrict__ wt, int K)
{
    int idx = blockIdx.x * 256 + threadIdx.x;
    int k = idx >> 8, n = idx & 255;
    wt[n * K + k] = (bf16_t)w[idx];
}

__global__ void bn_finalize(const float* __restrict__ stats,
                            const float* __restrict__ g, const float* __restrict__ beta,
                            float M, float* __restrict__ sc)
{
    int c = threadIdx.x;
    float mean = stats[c] / M;
    float var  = stats[H + c] / M - mean * mean;
    float scale = g[c] * rsqrtf(var + 1e-5f);
    sc[c]     = scale;
    sc[H + c] = beta[c] - mean * scale;
}

// out-of-place y = x*scale + shift (node tensors only, 1 MB)
__global__ void bn_apply(const bf16_t* __restrict__ x, bf16_t* __restrict__ y,
                         const float* __restrict__ sc, int nvec)
{
    int i = blockIdx.x * 256 + threadIdx.x;
    if (i >= nvec) return;
    bf16x8 v = ((const bf16x8*)x)[i];
    int cb = (i * 8) & 255;
    bf16x8 w;
#pragma unroll
    for (int j = 0; j < 8; ++j)
        w[j] = (bf16_t)((float)v[j] * sc[cb + j] + sc[H + cb + j]);
    ((bf16x8*)y)[i] = w;
}

// inc[b,n,:] = scale*(sum_recv h2)/64 + shift*63/64  (BN2 folded)
__global__ void edge2node(const bf16_t* __restrict__ x2, const float* __restrict__ sc,
                          bf16_t* __restrict__ inc)
{
    int bn = blockIdx.x, bb = bn >> 6, n = bn & 63;
    int g = threadIdx.x >> 5, t = threadIdx.x & 31;
    __shared__ float part[8][256];
    const bf16_t* base = x2 + (size_t)bb * EB * H;
    float a[8] = {0.f,0.f,0.f,0.f,0.f,0.f,0.f,0.f};
    for (int i = g; i < NB; i += 8) {
        if (i == n) continue;
        int e = i * (NB - 1) + n - (n > i ? 1 : 0);
        bf16x8 v = *(const bf16x8*)&base[(size_t)e * H + t * 8];
#pragma unroll
        for (int j = 0; j < 8; ++j) a[j] += (float)v[j];
    }
#pragma unroll
    for (int j = 0; j < 8; ++j) part[g][t * 8 + j] = a[j];
    __syncthreads();
    int c = threadIdx.x;
    float s = 0.f;
#pragma unroll
    for (int g2 = 0; g2 < 8; ++g2) s += part[g2][c];
    inc[(size_t)bn * H + c] = (bf16_t)(s * (1.f / 64.f) * sc[c] + sc[H + c] * (63.f / 64.f));
}

// out[m,0:2] = (h4[m,:]*scale+shift) @ fc_w + fc_b (BN4 folded), fp32 out
__global__ void fc_kernel(const bf16_t* __restrict__ x4, const float* __restrict__ sc,
                          const float* __restrict__ fcw, const float* __restrict__ fcb,
                          float* __restrict__ out)
{
    int row  = blockIdx.x * 8 + (threadIdx.x >> 5);
    int t    = threadIdx.x & 31;
    bf16x8 v8 = *(const bf16x8*)(x4 + (size_t)row * H + t * 8);
    float s0 = 0.f, s1 = 0.f;
#pragma unroll
    for (int j = 0; j < 8; ++j) {
        int c = t * 8 + j;
        float v = (float)v8[j] * sc[c] + sc[H + c];
        s0 += v * fcw[c * 2];
        s1 += v * fcw[c * 2 + 1];
    }
#pragma unroll
    for (int off = 16; off; off >>= 1) {
        s0 += __shfl_down(s0, off, 32);
        s1 += __shfl_down(s1, off, 32);
    }
    if (t == 0) {
        out[(size_t)row * 2]     = s0 + fcb[0];
        out[(size_t)row * 2 + 1] = s1 + fcb[1];
    }
}

// ---------------------------------------------------------------------------
extern "C" void kernel_launch(void* const* d_in, const int* in_sizes, int n_in,
                              void* d_out, int out_size, void* d_ws, size_t ws_size,
                              hipStream_t stream)
{
    (void)in_sizes; (void)n_in; (void)out_size; (void)ws_size;
    const float* inp = (const float*)d_in[0];
    const float* w1a = (const float*)d_in[3];  const float* b1a = (const float*)d_in[4];
    const float* w1b = (const float*)d_in[5];  const float* b1b = (const float*)d_in[6];
    const float* g1  = (const float*)d_in[7];  const float* be1 = (const float*)d_in[8];
    const float* w2a = (const float*)d_in[9];  const float* b2a = (const float*)d_in[10];
    const float* w2b = (const float*)d_in[11]; const float* b2b = (const float*)d_in[12];
    const float* g2  = (const float*)d_in[13]; const float* be2 = (const float*)d_in[14];
    const float* w3a = (const float*)d_in[15]; const float* b3a = (const float*)d_in[16];
    const float* w3b = (const float*)d_in[17]; const float* b3b = (const float*)d_in[18];
    const float* g3  = (const float*)d_in[19]; const float* be3 = (const float*)d_in[20];
    const float* w4a = (const float*)d_in[21]; const float* b4a = (const float*)d_in[22];
    const float* w4b = (const float*)d_in[23]; const float* b4b = (const float*)d_in[24];
    const float* g4  = (const float*)d_in[25]; const float* be4 = (const float*)d_in[26];
    const float* fcw = (const float*)d_in[27]; const float* fcb = (const float*)d_in[28];

    char* p = (char*)d_ws;
    auto alloc = [&](size_t nbytes) { char* r = p; p += (nbytes + 255) & ~(size_t)255; return r; };

    bf16_t* wt1a = (bf16_t*)alloc(256 * 256 * 2);
    bf16_t* wt1b = (bf16_t*)alloc(256 * 256 * 2);
    bf16_t* wt2a = (bf16_t*)alloc(512 * 256 * 2);
    bf16_t* wt2b = (bf16_t*)alloc(256 * 256 * 2);
    bf16_t* wt3a = (bf16_t*)alloc(256 * 256 * 2);
    bf16_t* wt3b = (bf16_t*)alloc(256 * 256 * 2);
    bf16_t* wt4a = (bf16_t*)alloc(768 * 256 * 2);
    bf16_t* wt4b = (bf16_t*)alloc(256 * 256 * 2);
    float*  stats = (float*)alloc(4 * 512 * sizeof(float));
    float*  sc    = (float*)alloc(4 * 512 * sizeof(float));
    bf16_t* x1   = (bf16_t*)alloc((size_t)M_NODE * H * 2);
    bf16_t* x1bn = (bf16_t*)alloc((size_t)M_NODE * H * 2);
    bf16_t* incb = (bf16_t*)alloc((size_t)M_NODE * H * 2);
    bf16_t* x3   = (bf16_t*)alloc((size_t)M_NODE * H * 2);
    bf16_t* x3bn = (bf16_t*)alloc((size_t)M_NODE * H * 2);
    bf16_t* bufA = (bf16_t*)alloc((size_t)M_EDGE * H * 2);
    bf16_t* bufB = (bf16_t*)alloc((size_t)M_EDGE * H * 2);

    zero_stats<<<8, 256, 0, stream>>>(stats);
    transpose_w<<<256, 256, 0, stream>>>(w1a, wt1a, 256);
    transpose_w<<<256, 256, 0, stream>>>(w1b, wt1b, 256);
    transpose_w<<<512, 256, 0, stream>>>(w2a, wt2a, 512);
    transpose_w<<<256, 256, 0, stream>>>(w2b, wt2b, 256);
    transpose_w<<<256, 256, 0, stream>>>(w3a, wt3a, 256);
    transpose_w<<<256, 256, 0, stream>>>(w3b, wt3b, 256);
    transpose_w<<<768, 256, 0, stream>>>(w4a, wt4a, 768);
    transpose_w<<<256, 256, 0, stream>>>(w4b, wt4b, 256);

    // MLP1 (nodes, fused L1+L2)
    fused_mlp<0, true ><<<M_NODE / 64, 256, 0, stream>>>(inp, nullptr, wt1a, b1a, wt1b, b1b, nullptr, x1, stats + 0, 256);
    bn_finalize<<<1, 256, 0, stream>>>(stats + 0, g1, be1, (float)M_NODE, sc + 0);
    bn_apply<<<M_NODE * H / 8 / 256, 256, 0, stream>>>(x1, x1bn, sc + 0, M_NODE * H / 8);

    // MLP2 (edges, fused, concat[send,recv] from x1bn) -> bufB = h2 raw
    fused_mlp<1, false><<<M_EDGE / 64, 256, 0, stream>>>(x1bn, nullptr, wt2a, b2a, wt2b, b2b, nullptr, bufB, stats + 512, 512);
    bn_finalize<<<1, 256, 0, stream>>>(stats + 512, g2, be2, (float)M_EDGE, sc + 512);

    // edge2node (BN2 folded) + MLP3 (nodes, fused)
    edge2node<<<M_NODE, 256, 0, stream>>>(bufB, sc + 512, incb);
    fused_mlp<0, false><<<M_NODE / 64, 256, 0, stream>>>(incb, nullptr, wt3a, b3a, wt3b, b3b, nullptr, x3, stats + 1024, 256);
    bn_finalize<<<1, 256, 0, stream>>>(stats + 1024, g3, be3, (float)M_NODE, sc + 1024);
    bn_apply<<<M_NODE * H / 8 / 256, 256, 0, stream>>>(x3, x3bn, sc + 1024, M_NODE * H / 8);

    // MLP4 (edges, fused, concat[send,recv from x3bn | skip=BN2(h2) inline]) -> bufA = h4 raw
    fused_mlp<2, false><<<M_EDGE / 64, 256, 0, stream>>>(x3bn, bufB, wt4a, b4a, wt4b, b4b, sc + 512, bufA, stats + 1536, 768);
    bn_finalize<<<1, 256, 0, stream>>>(stats + 1536, g4, be4, (float)M_EDGE, sc + 1536);

    // final fc with BN4 folded, fp32 output
    fc_kernel<<<M_EDGE / 8, 256, 0, stream>>>(bufA, sc + 1536, fcw, fcb, (float*)d_out);
}